// Round 1
// baseline (110.964 us; speedup 1.0000x reference)
//
#include <hip/hip_runtime.h>
#include <math.h>

#define BTOT 32768

__global__ __launch_bounds__(256) void vqc_net(
    const float* __restrict__ x,
    const float* __restrict__ W_pi1, const float* __restrict__ b_pi1,
    const float* __restrict__ qw_pi,
    const float* __restrict__ W_pi2, const float* __restrict__ b_pi2,
    const float* __restrict__ W_v1, const float* __restrict__ b_v1,
    const float* __restrict__ qw_v,
    const float* __restrict__ W_v2, const float* __restrict__ b_v2,
    float* __restrict__ out)
{
    __shared__ float ctab[2][2][8], stab[2][2][8];
    const int tid = threadIdx.x;
    if (tid < 32) {
        const int br = tid >> 4, k = (tid >> 3) & 1, q = tid & 7;
        const float w = (br ? qw_v : qw_pi)[k * 8 + q];
        float sv, cv;
        sincosf(0.5f * w, &sv, &cv);
        ctab[br][k][q] = cv;
        stab[br][k][q] = sv;
    }
    __syncthreads();

    const int wave = tid >> 6, lane = tid & 63;
    const int pair = blockIdx.x * 4 + wave;   // 0..65535
    const int branch = pair >> 15;            // 0 = pi, 1 = v
    const int s = pair & (BTOT - 1);

    const float* W1 = branch ? W_v1 : W_pi1;
    const float* b1 = branch ? b_v1 : b_pi1;

    // ---- embedding: per-qubit single-qubit state after H + RY(theta_q) ----
    // lane computes qubit (lane & 7); a = amp(bit=0) = cos(theta/2 + pi/4),
    // b = amp(bit=1) = sin(theta/2 + pi/4)
    float aq_, bq_;
    {
        const int q = lane & 7;
        const float* xr = x + s * 8;
        const float* wr = W1 + q * 8;
        float acc = b1[q];
        #pragma unroll
        for (int j = 0; j < 8; ++j) acc = fmaf(xr[j], wr[j], acc);
        const float theta = tanhf(acc);
        const float phi = 0.5f * theta + 0.785398163397448309f;
        sincosf(phi, &bq_, &aq_);
    }

    // ---- build product state: 4 amps/lane, flat idx = lane*4 + r ----
    // qubit q (0..5) <-> lane bit (5-q); qubit 6 <-> r bit1; qubit 7 <-> r bit0
    float f = 1.0f;
    #pragma unroll
    for (int q = 0; q < 6; ++q) {
        const float av = __shfl(aq_, q), bv = __shfl(bq_, q);
        f *= ((lane >> (5 - q)) & 1) ? bv : av;
    }
    const float a6 = __shfl(aq_, 6), b6 = __shfl(bq_, 6);
    const float a7 = __shfl(aq_, 7), b7 = __shfl(bq_, 7);
    float amp0 = f * a6 * a7, amp1 = f * a6 * b7;
    float amp2 = f * b6 * a7, amp3 = f * b6 * b7;

    auto cnot_ll = [&](int cbit, int tbit) {
        const float o0 = __shfl_xor(amp0, 1 << tbit);
        const float o1 = __shfl_xor(amp1, 1 << tbit);
        const float o2 = __shfl_xor(amp2, 1 << tbit);
        const float o3 = __shfl_xor(amp3, 1 << tbit);
        if ((lane >> cbit) & 1) { amp0 = o0; amp1 = o1; amp2 = o2; amp3 = o3; }
    };
    auto ry_ll = [&](int mbit, float c, float sv) {
        // bit=0 lane holds 'a': a' = c*a - s*b ; bit=1 lane holds 'b': b' = s*a + c*b
        const float ss = ((lane >> mbit) & 1) ? sv : -sv;
        const float o0 = __shfl_xor(amp0, 1 << mbit);
        const float o1 = __shfl_xor(amp1, 1 << mbit);
        const float o2 = __shfl_xor(amp2, 1 << mbit);
        const float o3 = __shfl_xor(amp3, 1 << mbit);
        amp0 = fmaf(c, amp0, ss * o0);
        amp1 = fmaf(c, amp1, ss * o1);
        amp2 = fmaf(c, amp2, ss * o2);
        amp3 = fmaf(c, amp3, ss * o3);
    };

    #pragma unroll
    for (int k = 0; k < 2; ++k) {
        cnot_ll(5, 4);   // CNOT(0,1)
        cnot_ll(3, 2);   // CNOT(2,3)
        cnot_ll(1, 0);   // CNOT(4,5)
        { const float t = amp2; amp2 = amp3; amp3 = t; }  // CNOT(6,7): r2<->r3
        cnot_ll(4, 3);   // CNOT(1,2)
        cnot_ll(2, 1);   // CNOT(3,4)
        if (lane & 1) {  // CNOT(5,6): ctl lane bit0, flip r bit1
            float t = amp0; amp0 = amp2; amp2 = t;
            t = amp1; amp1 = amp3; amp3 = t;
        }
        #pragma unroll
        for (int q = 0; q < 6; ++q)
            ry_ll(5 - q, ctab[branch][k][q], stab[branch][k][q]);
        {   // RY qubit 6: pairs (r0,r2),(r1,r3)
            const float c = ctab[branch][k][6], sv = stab[branch][k][6];
            const float n0 = fmaf(c, amp0, -sv * amp2);
            const float n2 = fmaf(sv, amp0, c * amp2);
            const float n1 = fmaf(c, amp1, -sv * amp3);
            const float n3 = fmaf(sv, amp1, c * amp3);
            amp0 = n0; amp2 = n2; amp1 = n1; amp3 = n3;
        }
        {   // RY qubit 7: pairs (r0,r1),(r2,r3)
            const float c = ctab[branch][k][7], sv = stab[branch][k][7];
            const float n0 = fmaf(c, amp0, -sv * amp1);
            const float n1 = fmaf(sv, amp0, c * amp1);
            const float n2 = fmaf(c, amp2, -sv * amp3);
            const float n3 = fmaf(sv, amp2, c * amp3);
            amp0 = n0; amp1 = n1; amp2 = n2; amp3 = n3;
        }
    }

    // ---- expectations <Z_q> = sum probs * (+1 if bit_q=0 else -1) ----
    const float p0 = amp0 * amp0, p1 = amp1 * amp1;
    const float p2 = amp2 * amp2, p3 = amp3 * amp3;
    const float tsum = p0 + p1 + p2 + p3;
    float v[8];
    #pragma unroll
    for (int q = 0; q < 6; ++q)
        v[q] = ((lane >> (5 - q)) & 1) ? -tsum : tsum;
    v[6] = (p0 + p1) - (p2 + p3);
    v[7] = (p0 - p1) + (p2 - p3);
    #pragma unroll
    for (int m = 1; m < 64; m <<= 1) {
        #pragma unroll
        for (int q = 0; q < 8; ++q)
            v[q] += __shfl_xor(v[q], m);
    }

    float y[8];
    #pragma unroll
    for (int q = 0; q < 8; ++q) y[q] = tanhf(v[q]);

    if (branch == 0) {
        if (lane < 4) {
            const float* wr = W_pi2 + lane * 8;
            float o = b_pi2[lane];
            #pragma unroll
            for (int j = 0; j < 8; ++j) o = fmaf(y[j], wr[j], o);
            out[s * 4 + lane] = o;
        }
    } else {
        if (lane == 0) {
            float o = b_v2[0];
            #pragma unroll
            for (int j = 0; j < 8; ++j) o = fmaf(y[j], W_v2[j], o);
            out[BTOT * 4 + s] = o;
        }
    }
}

extern "C" void kernel_launch(void* const* d_in, const int* in_sizes, int n_in,
                              void* d_out, int out_size, void* d_ws, size_t ws_size,
                              hipStream_t stream) {
    const float* x     = (const float*)d_in[0];
    const float* W_pi1 = (const float*)d_in[1];
    const float* b_pi1 = (const float*)d_in[2];
    const float* qw_pi = (const float*)d_in[3];
    const float* W_pi2 = (const float*)d_in[4];
    const float* b_pi2 = (const float*)d_in[5];
    const float* W_v1  = (const float*)d_in[6];
    const float* b_v1  = (const float*)d_in[7];
    const float* qw_v  = (const float*)d_in[8];
    const float* W_v2  = (const float*)d_in[9];
    const float* b_v2  = (const float*)d_in[10];
    float* out = (float*)d_out;

    // 2*B wave-pairs, 4 waves (256 threads) per block
    const int blocks = (2 * BTOT) / 4;
    vqc_net<<<blocks / 64 * 64 == blocks ? blocks : blocks, 256, 0, stream>>>(
        x, W_pi1, b_pi1, qw_pi, W_pi2, b_pi2,
        W_v1, b_v1, qw_v, W_v2, b_v2, out);
}

// Round 4
// 48.132 us; speedup vs baseline: 2.3054x; 2.3054x over previous
//
#include <hip/hip_runtime.h>
#include <math.h>

#define BTOT 32768

// ---- cross-lane helpers (VALU where possible) ----
template<int C>
__device__ __forceinline__ float xdpp(float x) {  // full-wave DPP move
    int xi = __float_as_int(x);
    return __int_as_float(__builtin_amdgcn_update_dpp(xi, xi, C, 0xF, 0xF, false));
}
#define XS1(v) xdpp<0xB1>(v)    // quad_perm [1,0,3,2]  = lane^1
#define XS2(v) xdpp<0x4E>(v)    // quad_perm [2,3,0,1]  = lane^2
#define XS8(v) xdpp<0x128>(v)   // row_ror:8            = lane^8 (rotate by 8 == xor 8)

__device__ __forceinline__ float XS4(float x) {   // lane^4 via ds_swizzle (documented 0x101F)
    return __int_as_float(__builtin_amdgcn_ds_swizzle(__float_as_int(x), 0x101F));
}
__device__ __forceinline__ float XS16(float x) {  // lane^16 via ds_swizzle (documented 0x401F)
    return __int_as_float(__builtin_amdgcn_ds_swizzle(__float_as_int(x), 0x401F));
}
__device__ __forceinline__ float XS32(float x) {  // lane^32 — toolchain-verified path (round 0)
    return __shfl_xor(x, 32);
}
__device__ __forceinline__ float bperm(int addr, float v) {
    return __int_as_float(__builtin_amdgcn_ds_bpermute(addr, __float_as_int(v)));
}
__device__ __forceinline__ float rlane(float v, int l) {
    return __int_as_float(__builtin_amdgcn_readlane(__float_as_int(v), l));
}
__device__ __forceinline__ float red64(float x) {  // full-wave sum -> lane 63 (canonical pattern)
    int t;
    t = __builtin_amdgcn_update_dpp(0, __float_as_int(x), 0xB1, 0xF, 0xF, false);  x += __int_as_float(t);
    t = __builtin_amdgcn_update_dpp(0, __float_as_int(x), 0x4E, 0xF, 0xF, false);  x += __int_as_float(t);
    t = __builtin_amdgcn_update_dpp(0, __float_as_int(x), 0x141, 0xF, 0xF, false); x += __int_as_float(t); // row_half_mirror
    t = __builtin_amdgcn_update_dpp(0, __float_as_int(x), 0x140, 0xF, 0xF, false); x += __int_as_float(t); // row_mirror
    t = __builtin_amdgcn_update_dpp(0, __float_as_int(x), 0x142, 0xA, 0xF, false); x += __int_as_float(t); // row_bcast15
    t = __builtin_amdgcn_update_dpp(0, __float_as_int(x), 0x143, 0xC, 0xF, false); x += __int_as_float(t); // row_bcast31
    return x;
}
__device__ __forceinline__ float ftanh(float x) {
    float e = __builtin_amdgcn_exp2f(x * 2.8853900817779268f);  // e^(2x)
    return (e - 1.0f) * __builtin_amdgcn_rcpf(e + 1.0f);
}

__global__ __launch_bounds__(256) void vqc_net(
    const float* __restrict__ x,
    const float* __restrict__ W_pi1, const float* __restrict__ b_pi1,
    const float* __restrict__ qw_pi,
    const float* __restrict__ W_pi2, const float* __restrict__ b_pi2,
    const float* __restrict__ W_v1, const float* __restrict__ b_v1,
    const float* __restrict__ qw_v,
    const float* __restrict__ W_v2, const float* __restrict__ b_v2,
    float* __restrict__ out)
{
    const int tid = threadIdx.x;
    const int lane = tid & 63;
    const int pair = blockIdx.x * 4 + (tid >> 6);  // 0..65535
    const int branch = pair >> 15;                 // 0 = pi, 1 = v
    const int s = pair & (BTOT - 1);

    // ---- circuit-weight table (lane l<16 computes, readlane broadcast) ----
    const float* qw = branch ? qw_v : qw_pi;
    float sg, cg;
    sincosf(0.5f * qw[lane & 15], &sg, &cg);
    float gc[16], gs[16];
    #pragma unroll
    for (int l = 0; l < 16; ++l) {
        gc[l] = rlane(cg, l);
        gs[l] = rlane(sg, l);
    }

    // ---- embedding: qubit (lane&7): a = cos(th/2+pi/4), b = sin(th/2+pi/4) ----
    const float* W1 = branch ? W_v1 : W_pi1;
    const float* b1 = branch ? b_v1 : b_pi1;
    float aq, bq;
    {
        const int q = lane & 7;
        const float* xr = x + s * 8;
        const float* wr = W1 + q * 8;
        float acc = b1[q];
        #pragma unroll
        for (int j = 0; j < 8; ++j) acc = fmaf(xr[j], wr[j], acc);
        const float theta = ftanh(acc);
        sincosf(0.5f * theta + 0.7853981633974483f, &bq, &aq);
    }
    float sa[8], sb[8];
    #pragma unroll
    for (int j = 0; j < 8; ++j) { sa[j] = rlane(aq, j); sb[j] = rlane(bq, j); }

    // ---- product state: idx = lane*4 + r; qubit q<6 <-> lane bit (5-q),
    //      qubit6 <-> r bit1, qubit7 <-> r bit0 ----
    float f = 1.0f;
    #pragma unroll
    for (int q = 0; q < 6; ++q)
        f *= ((lane >> (5 - q)) & 1) ? sb[q] : sa[q];
    const float ta = f * sa[6], tb = f * sb[6];
    float amp0 = ta * sa[7], amp1 = ta * sb[7];
    float amp2 = tb * sa[7], amp3 = tb * sb[7];

    // ---- precomputed lane data ----
    // group1: CNOT(0,1),(2,3),(4,5): ctl bits 5,3,1 -> tgt bits 4,2,0 (pull addr)
    const int a1 = (lane ^ ((((lane >> 5) & 1) << 4) | (((lane >> 3) & 1) << 2) | ((lane >> 1) & 1))) << 2;
    // group2: CNOT(1,2),(3,4): ctl bits 4,2 -> tgt bits 3,1
    const int a2 = (lane ^ ((((lane >> 4) & 1) << 3) | (((lane >> 2) & 1) << 1))) << 2;
    const bool c56 = lane & 1;  // qubit5 = lane bit 0 (control of CNOT(5,6))
    float sgn[6];
    #pragma unroll
    for (int mb = 0; mb < 6; ++mb) sgn[mb] = ((lane >> mb) & 1) ? 1.0f : -1.0f;

    #define RY_X(XSEXPR, C_, S_, SG) { \
        const float ss = (S_) * (SG); \
        const float o0 = XSEXPR(amp0), o1 = XSEXPR(amp1); \
        const float o2 = XSEXPR(amp2), o3 = XSEXPR(amp3); \
        amp0 = fmaf((C_), amp0, ss * o0); \
        amp1 = fmaf((C_), amp1, ss * o1); \
        amp2 = fmaf((C_), amp2, ss * o2); \
        amp3 = fmaf((C_), amp3, ss * o3); }

    #pragma unroll
    for (int k = 0; k < 2; ++k) {
        // even CNOT rank: (0,1),(2,3),(4,5) fused bpermute; (6,7) local swap
        amp0 = bperm(a1, amp0); amp1 = bperm(a1, amp1);
        amp2 = bperm(a1, amp2); amp3 = bperm(a1, amp3);
        { const float t = amp2; amp2 = amp3; amp3 = t; }
        // odd CNOT rank: (1,2),(3,4) fused bpermute; (5,6) local
        amp0 = bperm(a2, amp0); amp1 = bperm(a2, amp1);
        amp2 = bperm(a2, amp2); amp3 = bperm(a2, amp3);
        {
            const float n0 = c56 ? amp2 : amp0, n2 = c56 ? amp0 : amp2;
            const float n1 = c56 ? amp3 : amp1, n3 = c56 ? amp1 : amp3;
            amp0 = n0; amp1 = n1; amp2 = n2; amp3 = n3;
        }
        // RY on qubits 0..5 (lane-bit masks 32,16,8,4,2,1)
        RY_X(XS32, gc[k*8+0], gs[k*8+0], sgn[5]);
        RY_X(XS16, gc[k*8+1], gs[k*8+1], sgn[4]);
        RY_X(XS8,  gc[k*8+2], gs[k*8+2], sgn[3]);
        RY_X(XS4,  gc[k*8+3], gs[k*8+3], sgn[2]);
        RY_X(XS2,  gc[k*8+4], gs[k*8+4], sgn[1]);
        RY_X(XS1,  gc[k*8+5], gs[k*8+5], sgn[0]);
        {   // RY qubit 6: pairs (r0,r2),(r1,r3)
            const float c = gc[k*8+6], sv = gs[k*8+6];
            const float n0 = fmaf(c, amp0, -(sv * amp2));
            const float n2 = fmaf(sv, amp0,  (c * amp2));
            const float n1 = fmaf(c, amp1, -(sv * amp3));
            const float n3 = fmaf(sv, amp1,  (c * amp3));
            amp0 = n0; amp2 = n2; amp1 = n1; amp3 = n3;
        }
        {   // RY qubit 7: pairs (r0,r1),(r2,r3)
            const float c = gc[k*8+7], sv = gs[k*8+7];
            const float n0 = fmaf(c, amp0, -(sv * amp1));
            const float n1 = fmaf(sv, amp0,  (c * amp1));
            const float n2 = fmaf(c, amp2, -(sv * amp3));
            const float n3 = fmaf(sv, amp2,  (c * amp3));
            amp0 = n0; amp1 = n1; amp2 = n2; amp3 = n3;
        }
    }

    // ---- expectations ----
    const float p0 = amp0 * amp0, p1 = amp1 * amp1;
    const float p2 = amp2 * amp2, p3 = amp3 * amp3;
    const float tsum = (p0 + p1) + (p2 + p3);

    // FWHT butterfly: new = partner + sgn2*self, sgn2 = (bit set ? -1 : +1) = -sgn[]
    // lane (1<<(5-q)) ends with <Z_q> (q = 0..5)
    float w = tsum;
    w = fmaf(-sgn[5], w, XS32(w));
    w = fmaf(-sgn[4], w, XS16(w));
    w = fmaf(-sgn[3], w, XS8(w));
    w = fmaf(-sgn[2], w, XS4(w));
    w = fmaf(-sgn[1], w, XS2(w));
    w = fmaf(-sgn[0], w, XS1(w));
    const float th = ftanh(w);
    const float y0 = rlane(th, 32), y1 = rlane(th, 16), y2 = rlane(th, 8);
    const float y3 = rlane(th, 4),  y4 = rlane(th, 2),  y5 = rlane(th, 1);

    const float v6 = (p0 + p1) - (p2 + p3);
    const float v7 = (p0 - p1) + (p2 - p3);
    const float y6 = rlane(ftanh(red64(v6)), 63);
    const float y7 = rlane(ftanh(red64(v7)), 63);

    // ---- output matvec (y* are wave-uniform) ----
    if (branch == 0) {
        if (lane < 4) {
            const float* wr2 = W_pi2 + lane * 8;
            float o = b_pi2[lane];
            o = fmaf(y0, wr2[0], o); o = fmaf(y1, wr2[1], o);
            o = fmaf(y2, wr2[2], o); o = fmaf(y3, wr2[3], o);
            o = fmaf(y4, wr2[4], o); o = fmaf(y5, wr2[5], o);
            o = fmaf(y6, wr2[6], o); o = fmaf(y7, wr2[7], o);
            out[s * 4 + lane] = o;
        }
    } else {
        if (lane == 0) {
            float o = b_v2[0];
            o = fmaf(y0, W_v2[0], o); o = fmaf(y1, W_v2[1], o);
            o = fmaf(y2, W_v2[2], o); o = fmaf(y3, W_v2[3], o);
            o = fmaf(y4, W_v2[4], o); o = fmaf(y5, W_v2[5], o);
            o = fmaf(y6, W_v2[6], o); o = fmaf(y7, W_v2[7], o);
            out[BTOT * 4 + s] = o;
        }
    }
}

extern "C" void kernel_launch(void* const* d_in, const int* in_sizes, int n_in,
                              void* d_out, int out_size, void* d_ws, size_t ws_size,
                              hipStream_t stream) {
    const float* x     = (const float*)d_in[0];
    const float* W_pi1 = (const float*)d_in[1];
    const float* b_pi1 = (const float*)d_in[2];
    const float* qw_pi = (const float*)d_in[3];
    const float* W_pi2 = (const float*)d_in[4];
    const float* b_pi2 = (const float*)d_in[5];
    const float* W_v1  = (const float*)d_in[6];
    const float* b_v1  = (const float*)d_in[7];
    const float* qw_v  = (const float*)d_in[8];
    const float* W_v2  = (const float*)d_in[9];
    const float* b_v2  = (const float*)d_in[10];
    float* out = (float*)d_out;

    const int blocks = (2 * BTOT) / 4;  // 4 waves per block, 1 sample-branch per wave
    vqc_net<<<blocks, 256, 0, stream>>>(
        x, W_pi1, b_pi1, qw_pi, W_pi2, b_pi2,
        W_v1, b_v1, qw_v, W_v2, b_v2, out);
}

// Round 5
// 46.802 us; speedup vs baseline: 2.3710x; 1.0284x over previous
//
#include <hip/hip_runtime.h>

#define BTOT 32768
#define INV2PI 0.15915494309189535f

// ---- cross-lane helpers (verified in round 4) ----
template<int C>
__device__ __forceinline__ float xdpp(float x) {  // full-wave DPP move
    int xi = __float_as_int(x);
    return __int_as_float(__builtin_amdgcn_update_dpp(xi, xi, C, 0xF, 0xF, false));
}
#define XS1(v) xdpp<0xB1>(v)    // quad_perm [1,0,3,2]  = lane^1
#define XS2(v) xdpp<0x4E>(v)    // quad_perm [2,3,0,1]  = lane^2
#define XS8(v) xdpp<0x128>(v)   // row_ror:8            = lane^8

__device__ __forceinline__ float XS4(float x) {   // lane^4 via ds_swizzle (0x101F)
    return __int_as_float(__builtin_amdgcn_ds_swizzle(__float_as_int(x), 0x101F));
}
__device__ __forceinline__ float XS16(float x) {  // lane^16 via ds_swizzle (0x401F)
    return __int_as_float(__builtin_amdgcn_ds_swizzle(__float_as_int(x), 0x401F));
}
__device__ __forceinline__ float XS32(float x) {  // lane^32
    return __shfl_xor(x, 32);
}
__device__ __forceinline__ float bperm(int addr, float v) {
    return __int_as_float(__builtin_amdgcn_ds_bpermute(addr, __float_as_int(v)));
}
__device__ __forceinline__ float rlane(float v, int l) {
    return __int_as_float(__builtin_amdgcn_readlane(__float_as_int(v), l));
}
__device__ __forceinline__ float red64(float x) {  // full-wave sum -> lane 63
    int t;
    t = __builtin_amdgcn_update_dpp(0, __float_as_int(x), 0xB1, 0xF, 0xF, false);  x += __int_as_float(t);
    t = __builtin_amdgcn_update_dpp(0, __float_as_int(x), 0x4E, 0xF, 0xF, false);  x += __int_as_float(t);
    t = __builtin_amdgcn_update_dpp(0, __float_as_int(x), 0x141, 0xF, 0xF, false); x += __int_as_float(t); // row_half_mirror
    t = __builtin_amdgcn_update_dpp(0, __float_as_int(x), 0x140, 0xF, 0xF, false); x += __int_as_float(t); // row_mirror
    t = __builtin_amdgcn_update_dpp(0, __float_as_int(x), 0x142, 0xA, 0xF, false); x += __int_as_float(t); // row_bcast15
    t = __builtin_amdgcn_update_dpp(0, __float_as_int(x), 0x143, 0xC, 0xF, false); x += __int_as_float(t); // row_bcast31
    return x;
}
__device__ __forceinline__ float ftanh(float x) {
    float e = __builtin_amdgcn_exp2f(x * 2.8853900817779268f);  // e^(2x)
    return (e - 1.0f) * __builtin_amdgcn_rcpf(e + 1.0f);
}

__global__ __launch_bounds__(256) void vqc_net(
    const float* __restrict__ x,
    const float* __restrict__ W_pi1, const float* __restrict__ b_pi1,
    const float* __restrict__ qw_pi,
    const float* __restrict__ W_pi2, const float* __restrict__ b_pi2,
    const float* __restrict__ W_v1, const float* __restrict__ b_v1,
    const float* __restrict__ qw_v,
    const float* __restrict__ W_v2, const float* __restrict__ b_v2,
    float* __restrict__ out)
{
    const int tid = threadIdx.x;
    const int lane = tid & 63;
    const int pair = blockIdx.x * 4 + (tid >> 6);  // 0..65535
    const int branch = pair >> 15;                 // 0 = pi, 1 = v
    const int s = pair & (BTOT - 1);

    // ---- circuit-weight table: hw trig (revolutions), readlane broadcast ----
    const float* qw = branch ? qw_v : qw_pi;
    const float ang = 0.5f * qw[lane & 15] * INV2PI;
    const float cg = __builtin_amdgcn_cosf(ang);
    const float sg = __builtin_amdgcn_sinf(ang);
    float gc[16], gs[16];
    #pragma unroll
    for (int l = 0; l < 16; ++l) {
        gc[l] = rlane(cg, l);
        gs[l] = rlane(sg, l);
    }

    // ---- embedding: qubit (lane&7): a = cos(th/2+pi/4), b = sin(th/2+pi/4) ----
    const float* W1 = branch ? W_v1 : W_pi1;
    const float* b1 = branch ? b_v1 : b_pi1;
    float aq, bq;
    {
        const int q = lane & 7;
        const float4* xr4 = (const float4*)(x + s * 8);
        const float4 xa = xr4[0], xb = xr4[1];
        const float4* wr4 = (const float4*)(W1 + q * 8);
        const float4 wa = wr4[0], wb = wr4[1];
        float acc = b1[q];
        acc = fmaf(xa.x, wa.x, acc); acc = fmaf(xa.y, wa.y, acc);
        acc = fmaf(xa.z, wa.z, acc); acc = fmaf(xa.w, wa.w, acc);
        acc = fmaf(xb.x, wb.x, acc); acc = fmaf(xb.y, wb.y, acc);
        acc = fmaf(xb.z, wb.z, acc); acc = fmaf(xb.w, wb.w, acc);
        const float theta = ftanh(acc);
        // (0.5*theta + pi/4) in revolutions = theta*(INV2PI/2) + 1/8
        const float rev = fmaf(theta, 0.5f * INV2PI, 0.125f);
        aq = __builtin_amdgcn_cosf(rev);
        bq = __builtin_amdgcn_sinf(rev);
    }
    float sa[8], sb[8];
    #pragma unroll
    for (int j = 0; j < 8; ++j) { sa[j] = rlane(aq, j); sb[j] = rlane(bq, j); }

    // ---- product state: idx = lane*4 + r; qubit q<6 <-> lane bit (5-q),
    //      qubit6 <-> r bit1, qubit7 <-> r bit0 ----
    float f = 1.0f;
    #pragma unroll
    for (int q = 0; q < 6; ++q)
        f *= ((lane >> (5 - q)) & 1) ? sb[q] : sa[q];
    const float ta = f * sa[6], tb = f * sb[6];
    float amp0 = ta * sa[7], amp1 = ta * sb[7];
    float amp2 = tb * sa[7], amp3 = tb * sb[7];

    // ---- fused CNOT lane permutation (P2 o P1), addr = g1(g2(lane))<<2 ----
    // P1: CNOT(0,1),(2,3),(4,5): flip bits 4,2,0 per ctl bits 5,3,1
    // P2: CNOT(1,2),(3,4):       flip bits 3,1   per ctl bits 4,2
    const int L2v = lane ^ (((((lane >> 4) & 1) << 3) | (((lane >> 2) & 1) << 1)));
    const int a12 = (L2v ^ ((((L2v >> 5) & 1) << 4) | (((L2v >> 3) & 1) << 2) | ((L2v >> 1) & 1))) << 2;
    const bool c56 = lane & 1;  // qubit5 = lane bit 0 (control of CNOT(5,6))
    float sgn[6];
    #pragma unroll
    for (int mb = 0; mb < 6; ++mb) sgn[mb] = ((lane >> mb) & 1) ? 1.0f : -1.0f;

    #define RY_X(XSEXPR, C_, S_, SG) { \
        const float ss = (S_) * (SG); \
        const float o0 = XSEXPR(amp0), o1 = XSEXPR(amp1); \
        const float o2 = XSEXPR(amp2), o3 = XSEXPR(amp3); \
        amp0 = fmaf((C_), amp0, ss * o0); \
        amp1 = fmaf((C_), amp1, ss * o1); \
        amp2 = fmaf((C_), amp2, ss * o2); \
        amp3 = fmaf((C_), amp3, ss * o3); }

    #pragma unroll
    for (int k = 0; k < 2; ++k) {
        // all lane-bit CNOTs of the layer: one fused bpermute per reg
        amp0 = bperm(a12, amp0); amp1 = bperm(a12, amp1);
        amp2 = bperm(a12, amp2); amp3 = bperm(a12, amp3);
        // L1: CNOT(6,7) -> swap r2,r3 (commutes past P2: reg-plane op)
        { const float t = amp2; amp2 = amp3; amp3 = t; }
        // L2: CNOT(5,6) -> cond swap (r0,r2),(r1,r3) on lane bit0
        {
            const float n0 = c56 ? amp2 : amp0, n2 = c56 ? amp0 : amp2;
            const float n1 = c56 ? amp3 : amp1, n3 = c56 ? amp1 : amp3;
            amp0 = n0; amp1 = n1; amp2 = n2; amp3 = n3;
        }
        // RY on qubits 0..5 (lane-bit masks 32,16,8,4,2,1)
        RY_X(XS32, gc[k*8+0], gs[k*8+0], sgn[5]);
        RY_X(XS16, gc[k*8+1], gs[k*8+1], sgn[4]);
        RY_X(XS8,  gc[k*8+2], gs[k*8+2], sgn[3]);
        RY_X(XS4,  gc[k*8+3], gs[k*8+3], sgn[2]);
        RY_X(XS2,  gc[k*8+4], gs[k*8+4], sgn[1]);
        RY_X(XS1,  gc[k*8+5], gs[k*8+5], sgn[0]);
        {   // RY qubit 6: pairs (r0,r2),(r1,r3)
            const float c = gc[k*8+6], sv = gs[k*8+6];
            const float n0 = fmaf(c, amp0, -(sv * amp2));
            const float n2 = fmaf(sv, amp0,  (c * amp2));
            const float n1 = fmaf(c, amp1, -(sv * amp3));
            const float n3 = fmaf(sv, amp1,  (c * amp3));
            amp0 = n0; amp2 = n2; amp1 = n1; amp3 = n3;
        }
        {   // RY qubit 7: pairs (r0,r1),(r2,r3)
            const float c = gc[k*8+7], sv = gs[k*8+7];
            const float n0 = fmaf(c, amp0, -(sv * amp1));
            const float n1 = fmaf(sv, amp0,  (c * amp1));
            const float n2 = fmaf(c, amp2, -(sv * amp3));
            const float n3 = fmaf(sv, amp2,  (c * amp3));
            amp0 = n0; amp1 = n1; amp2 = n2; amp3 = n3;
        }
    }

    // ---- expectations ----
    const float p0 = amp0 * amp0, p1 = amp1 * amp1;
    const float p2 = amp2 * amp2, p3 = amp3 * amp3;
    const float tsum = (p0 + p1) + (p2 + p3);

    // FWHT butterfly: new = partner + sgn2*self, sgn2 = (bit set ? -1 : +1) = -sgn[]
    // lane (1<<(5-q)) ends with <Z_q> (q = 0..5)
    float w = tsum;
    w = fmaf(-sgn[5], w, XS32(w));
    w = fmaf(-sgn[4], w, XS16(w));
    w = fmaf(-sgn[3], w, XS8(w));
    w = fmaf(-sgn[2], w, XS4(w));
    w = fmaf(-sgn[1], w, XS2(w));
    w = fmaf(-sgn[0], w, XS1(w));
    const float th = ftanh(w);
    const float y0 = rlane(th, 32), y1 = rlane(th, 16), y2 = rlane(th, 8);
    const float y3 = rlane(th, 4),  y4 = rlane(th, 2),  y5 = rlane(th, 1);

    const float v6 = (p0 + p1) - (p2 + p3);
    const float v7 = (p0 - p1) + (p2 - p3);
    const float y6 = rlane(ftanh(red64(v6)), 63);
    const float y7 = rlane(ftanh(red64(v7)), 63);

    // ---- output matvec (y* are wave-uniform) ----
    if (branch == 0) {
        if (lane < 4) {
            const float4* wr2 = (const float4*)(W_pi2 + lane * 8);
            const float4 u0 = wr2[0], u1 = wr2[1];
            float o = b_pi2[lane];
            o = fmaf(y0, u0.x, o); o = fmaf(y1, u0.y, o);
            o = fmaf(y2, u0.z, o); o = fmaf(y3, u0.w, o);
            o = fmaf(y4, u1.x, o); o = fmaf(y5, u1.y, o);
            o = fmaf(y6, u1.z, o); o = fmaf(y7, u1.w, o);
            out[s * 4 + lane] = o;
        }
    } else {
        if (lane == 0) {
            const float4* wr2 = (const float4*)W_v2;
            const float4 u0 = wr2[0], u1 = wr2[1];
            float o = b_v2[0];
            o = fmaf(y0, u0.x, o); o = fmaf(y1, u0.y, o);
            o = fmaf(y2, u0.z, o); o = fmaf(y3, u0.w, o);
            o = fmaf(y4, u1.x, o); o = fmaf(y5, u1.y, o);
            o = fmaf(y6, u1.z, o); o = fmaf(y7, u1.w, o);
            out[BTOT * 4 + s] = o;
        }
    }
}

extern "C" void kernel_launch(void* const* d_in, const int* in_sizes, int n_in,
                              void* d_out, int out_size, void* d_ws, size_t ws_size,
                              hipStream_t stream) {
    const float* x     = (const float*)d_in[0];
    const float* W_pi1 = (const float*)d_in[1];
    const float* b_pi1 = (const float*)d_in[2];
    const float* qw_pi = (const float*)d_in[3];
    const float* W_pi2 = (const float*)d_in[4];
    const float* b_pi2 = (const float*)d_in[5];
    const float* W_v1  = (const float*)d_in[6];
    const float* b_v1  = (const float*)d_in[7];
    const float* qw_v  = (const float*)d_in[8];
    const float* W_v2  = (const float*)d_in[9];
    const float* b_v2  = (const float*)d_in[10];
    float* out = (float*)d_out;

    const int blocks = (2 * BTOT) / 4;  // 4 waves per block, 1 sample-branch per wave
    vqc_net<<<blocks, 256, 0, stream>>>(
        x, W_pi1, b_pi1, qw_pi, W_pi2, b_pi2,
        W_v1, b_v1, qw_v, W_v2, b_v2, out);
}

// Round 6
// 36.831 us; speedup vs baseline: 3.0128x; 1.2707x over previous
//
#include <hip/hip_runtime.h>

#define BTOT 32768
#define INV2PI 0.15915494309189535f

typedef float v2f __attribute__((ext_vector_type(2)));

__device__ __forceinline__ v2f mk2(float a, float b) { v2f r; r.x = a; r.y = b; return r; }

#if __has_builtin(__builtin_elementwise_fma)
__device__ __forceinline__ v2f fma2(v2f a, v2f b, v2f c) { return __builtin_elementwise_fma(a, b, c); }
#else
__device__ __forceinline__ v2f fma2(v2f a, v2f b, v2f c) {
    return mk2(fmaf(a.x, b.x, c.x), fmaf(a.y, b.y, c.y));
}
#endif

// ---- cross-lane helpers ----
// ds_swizzle xor patterns (ISA-documented family; 0x101F/0x401F HW-verified round 4)
template<int PAT>
__device__ __forceinline__ float dswz(float x) {
    return __int_as_float(__builtin_amdgcn_ds_swizzle(__float_as_int(x), PAT));
}
#define XS1(v)  dswz<0x041F>(v)   // lane^1
#define XS2(v)  dswz<0x081F>(v)   // lane^2
#define XS4(v)  dswz<0x101F>(v)   // lane^4
#define XS8(v)  dswz<0x201F>(v)   // lane^8
#define XS16(v) dswz<0x401F>(v)   // lane^16
__device__ __forceinline__ float XS32(float x) {  // lane^32 (verified)
    return __shfl_xor(x, 32);
}
__device__ __forceinline__ float bperm(int addr, float v) {
    return __int_as_float(__builtin_amdgcn_ds_bpermute(addr, __float_as_int(v)));
}
__device__ __forceinline__ float rlane(float v, int l) {
    return __int_as_float(__builtin_amdgcn_readlane(__float_as_int(v), l));
}
__device__ __forceinline__ float ftanh(float x) {
    float e = __builtin_amdgcn_exp2f(x * 2.8853900817779268f);  // e^(2x)
    return (e - 1.0f) * __builtin_amdgcn_rcpf(e + 1.0f);
}

__global__ __launch_bounds__(256) void vqc_net(
    const float* __restrict__ x,
    const float* __restrict__ W_pi1, const float* __restrict__ b_pi1,
    const float* __restrict__ qw_pi,
    const float* __restrict__ W_pi2, const float* __restrict__ b_pi2,
    const float* __restrict__ W_v1, const float* __restrict__ b_v1,
    const float* __restrict__ qw_v,
    const float* __restrict__ W_v2, const float* __restrict__ b_v2,
    float* __restrict__ out)
{
    const int tid = threadIdx.x;
    const int lane = tid & 63;
    const int pair = blockIdx.x * 4 + (tid >> 6);  // 0..65535
    const int branch = pair >> 15;                 // 0 = pi, 1 = v
    const int s = pair & (BTOT - 1);

    // ---- circuit-weight table: hw trig (revolutions), readlane broadcast ----
    const float* qw = branch ? qw_v : qw_pi;
    const float ang = 0.5f * qw[lane & 15] * INV2PI;
    const float cg = __builtin_amdgcn_cosf(ang);
    const float sg = __builtin_amdgcn_sinf(ang);
    float gc[16], gs[16];
    #pragma unroll
    for (int l = 0; l < 16; ++l) {
        gc[l] = rlane(cg, l);
        gs[l] = rlane(sg, l);
    }

    // ---- embedding: qubit (lane&7): a = cos(th/2+pi/4), b = sin(th/2+pi/4) ----
    const float* W1 = branch ? W_v1 : W_pi1;
    const float* b1 = branch ? b_v1 : b_pi1;
    float aq, bq;
    {
        const int q = lane & 7;
        const float4* xr4 = (const float4*)(x + s * 8);
        const float4 xa = xr4[0], xb = xr4[1];
        const float4* wr4 = (const float4*)(W1 + q * 8);
        const float4 wa = wr4[0], wb = wr4[1];
        float acc = b1[q];
        acc = fmaf(xa.x, wa.x, acc); acc = fmaf(xa.y, wa.y, acc);
        acc = fmaf(xa.z, wa.z, acc); acc = fmaf(xa.w, wa.w, acc);
        acc = fmaf(xb.x, wb.x, acc); acc = fmaf(xb.y, wb.y, acc);
        acc = fmaf(xb.z, wb.z, acc); acc = fmaf(xb.w, wb.w, acc);
        const float theta = ftanh(acc);
        const float rev = fmaf(theta, 0.5f * INV2PI, 0.125f);  // (th/2 + pi/4) in revolutions
        aq = __builtin_amdgcn_cosf(rev);
        bq = __builtin_amdgcn_sinf(rev);
    }
    float sa[8], sb[8];
    #pragma unroll
    for (int j = 0; j < 8; ++j) { sa[j] = rlane(aq, j); sb[j] = rlane(bq, j); }

    // ---- product state: idx = lane*4 + r; qubit q<6 <-> lane bit (5-q),
    //      qubit6 <-> r bit1, qubit7 <-> r bit0 ----
    float f = 1.0f;
    #pragma unroll
    for (int q = 0; q < 6; ++q)
        f *= ((lane >> (5 - q)) & 1) ? sb[q] : sa[q];
    const float ta = f * sa[6], tb = f * sb[6];
    v2f A01 = mk2(ta, ta) * mk2(sa[7], sb[7]);   // {amp0, amp1}
    v2f A23 = mk2(tb, tb) * mk2(sa[7], sb[7]);   // {amp2, amp3}

    // ---- fused CNOT lane permutation (P2 o P1), addr = g1(g2(lane))<<2 ----
    const int L2v = lane ^ (((((lane >> 4) & 1) << 3) | (((lane >> 2) & 1) << 1)));
    const int a12 = (L2v ^ ((((L2v >> 5) & 1) << 4) | (((L2v >> 3) & 1) << 2) | ((L2v >> 1) & 1))) << 2;
    const bool c56 = lane & 1;  // qubit5 = lane bit 0 (control of CNOT(5,6))
    float sgn[6];
    #pragma unroll
    for (int mb = 0; mb < 6; ++mb) sgn[mb] = ((lane >> mb) & 1) ? 1.0f : -1.0f;

    // packed lane-bit RY: A = C*A + (S*sgn)*shuffle(A), per float2 pair
    #define RY_P(XSEXPR, C_, S_, SG) { \
        const float ss = (S_) * (SG); \
        const v2f o01 = mk2(XSEXPR(A01.x), XSEXPR(A01.y)); \
        const v2f o23 = mk2(XSEXPR(A23.x), XSEXPR(A23.y)); \
        const v2f cv = mk2((C_), (C_)), sv = mk2(ss, ss); \
        A01 = fma2(cv, A01, sv * o01); \
        A23 = fma2(cv, A23, sv * o23); }

    #pragma unroll
    for (int k = 0; k < 2; ++k) {
        // all lane-bit CNOTs of the layer: one fused bpermute per 32-bit reg
        A01 = mk2(bperm(a12, A01.x), bperm(a12, A01.y));
        A23 = mk2(bperm(a12, A23.x), bperm(a12, A23.y));
        // CNOT(6,7): swap r2<->r3 (reg-plane, commutes past P2)
        A23 = mk2(A23.y, A23.x);
        // CNOT(5,6): cond swap (r0,r2),(r1,r3) on lane bit0
        {
            const v2f n01 = c56 ? A23 : A01;
            const v2f n23 = c56 ? A01 : A23;
            A01 = n01; A23 = n23;
        }
        // RY on qubits 0..5 (lane-bit masks 32,16,8,4,2,1)
        RY_P(XS32, gc[k*8+0], gs[k*8+0], sgn[5]);
        RY_P(XS16, gc[k*8+1], gs[k*8+1], sgn[4]);
        RY_P(XS8,  gc[k*8+2], gs[k*8+2], sgn[3]);
        RY_P(XS4,  gc[k*8+3], gs[k*8+3], sgn[2]);
        RY_P(XS2,  gc[k*8+4], gs[k*8+4], sgn[1]);
        RY_P(XS1,  gc[k*8+5], gs[k*8+5], sgn[0]);
        {   // RY qubit 6: pairs (r0,r2),(r1,r3) — componentwise across A01/A23
            const float c = gc[k*8+6], sv = gs[k*8+6];
            const v2f cc = mk2(c, c), ssv = mk2(sv, sv);
            const v2f n01 = fma2(cc, A01, -ssv * A23);
            const v2f n23 = fma2(ssv, A01, cc * A23);
            A01 = n01; A23 = n23;
        }
        {   // RY qubit 7: pairs (r0,r1),(r2,r3) — within-pair rotation
            const float c = gc[k*8+7], sv = gs[k*8+7];
            const v2f cs  = mk2(c, sv);
            const v2f msc = mk2(-sv, c);
            A01 = fma2(cs, mk2(A01.x, A01.x), msc * mk2(A01.y, A01.y));
            A23 = fma2(cs, mk2(A23.x, A23.x), msc * mk2(A23.y, A23.y));
        }
    }

    // ---- expectations ----
    const v2f P01 = A01 * A01, P23 = A23 * A23;
    const float s01 = P01.x + P01.y, s23 = P23.x + P23.y;
    const float d01 = P01.x - P01.y, d23 = P23.x - P23.y;
    const float tsum = s01 + s23;

    // FWHT butterfly (verified): new = partner + (-sgn)*self
    // lane (1<<(5-q)) ends with <Z_q> (q = 0..5)
    float w = tsum;
    w = fmaf(-sgn[5], w, XS32(w));
    w = fmaf(-sgn[4], w, XS16(w));
    w = fmaf(-sgn[3], w, XS8(w));
    w = fmaf(-sgn[2], w, XS4(w));
    w = fmaf(-sgn[1], w, XS2(w));
    w = fmaf(-sgn[0], w, XS1(w));
    const float th = ftanh(w);
    const float y0 = rlane(th, 32), y1 = rlane(th, 16), y2 = rlane(th, 8);
    const float y3 = rlane(th, 4),  y4 = rlane(th, 2),  y5 = rlane(th, 1);

    // packed {v6,v7} full-wave butterfly sum (all lanes get totals)
    v2f V = mk2(s01 - s23, d01 + d23);
    V += mk2(XS1(V.x),  XS1(V.y));
    V += mk2(XS2(V.x),  XS2(V.y));
    V += mk2(XS4(V.x),  XS4(V.y));
    V += mk2(XS8(V.x),  XS8(V.y));
    V += mk2(XS16(V.x), XS16(V.y));
    V += mk2(XS32(V.x), XS32(V.y));
    const float y6 = ftanh(V.x);
    const float y7 = ftanh(V.y);

    // ---- output matvec ----
    if (branch == 0) {
        if (lane < 4) {
            const float4* wr2 = (const float4*)(W_pi2 + lane * 8);
            const float4 u0 = wr2[0], u1 = wr2[1];
            float o = b_pi2[lane];
            o = fmaf(y0, u0.x, o); o = fmaf(y1, u0.y, o);
            o = fmaf(y2, u0.z, o); o = fmaf(y3, u0.w, o);
            o = fmaf(y4, u1.x, o); o = fmaf(y5, u1.y, o);
            o = fmaf(y6, u1.z, o); o = fmaf(y7, u1.w, o);
            out[s * 4 + lane] = o;
        }
    } else {
        if (lane == 0) {
            const float4* wr2 = (const float4*)W_v2;
            const float4 u0 = wr2[0], u1 = wr2[1];
            float o = b_v2[0];
            o = fmaf(y0, u0.x, o); o = fmaf(y1, u0.y, o);
            o = fmaf(y2, u0.z, o); o = fmaf(y3, u0.w, o);
            o = fmaf(y4, u1.x, o); o = fmaf(y5, u1.y, o);
            o = fmaf(y6, u1.z, o); o = fmaf(y7, u1.w, o);
            out[BTOT * 4 + s] = o;
        }
    }
}

extern "C" void kernel_launch(void* const* d_in, const int* in_sizes, int n_in,
                              void* d_out, int out_size, void* d_ws, size_t ws_size,
                              hipStream_t stream) {
    const float* x     = (const float*)d_in[0];
    const float* W_pi1 = (const float*)d_in[1];
    const float* b_pi1 = (const float*)d_in[2];
    const float* qw_pi = (const float*)d_in[3];
    const float* W_pi2 = (const float*)d_in[4];
    const float* b_pi2 = (const float*)d_in[5];
    const float* W_v1  = (const float*)d_in[6];
    const float* b_v1  = (const float*)d_in[7];
    const float* qw_v  = (const float*)d_in[8];
    const float* W_v2  = (const float*)d_in[9];
    const float* b_v2  = (const float*)d_in[10];
    float* out = (float*)d_out;

    const int blocks = (2 * BTOT) / 4;  // 4 waves per block, 1 sample-branch per wave
    vqc_net<<<blocks, 256, 0, stream>>>(
        x, W_pi1, b_pi1, qw_pi, W_pi2, b_pi2,
        W_v1, b_v1, qw_v, W_v2, b_v2, out);
}

// Round 7
// 16.711 us; speedup vs baseline: 6.6403x; 2.2040x over previous
//
#include <hip/hip_runtime.h>

#define BTOT 32768
#define INV2PI 0.15915494309189535f

// ======== compile-time Pauli algebra (Heisenberg back-propagation) ========
// Pauli codes: 0=I, 1=X, 2=Y, 3=Z. Strings packed 2 bits/qubit (qubit j at bits 2j).
namespace ct {
constexpr int PMUL[4][4] = {{0,1,2,3},{1,0,3,2},{2,3,0,1},{3,2,1,0}};
constexpr int PPH [4][4] = {{0,0,0,0},{0,0,1,3},{0,3,0,1},{0,1,3,0}};  // phase as power of i

// Conjugation images through one CNOT block (odd rank then even rank, backward):
// A_j = image of Z_j, B_j = image of X_j.  (Derived + re-verified by hand.)
constexpr unsigned A_STR[8] = {0x3u, 0xFu, 0x3Fu, 0xF0u, 0x3F0u, 0xF00u, 0x3F00u, 0xF000u};
// Z0 | Z0Z1 | Z0Z1Z2 | Z2Z3 | Z2Z3Z4 | Z4Z5 | Z4Z5Z6 | Z6Z7
constexpr unsigned B_STR[8] = {0x5u, 0x54u, 0x50u, 0x540u, 0x500u, 0x5400u, 0x5000u, 0x4000u};
// X0X1 | X1X2X3 | X2X3 | X3X4X5 | X4X5 | X5X6X7 | X6X7 | X7

struct Terms {
    int n; int w; int supp[3];
    float sgn[8]; unsigned char sbits[8]; unsigned char xm[8]; unsigned char zm[8];
};

// Expand Prod_{j in supp(base)} G_j where
//  Z-type factor: c1j*A_j - s1j*B_j ;  X-type factor: c1j*B_j + s1j*A_j.
// Multiply Pauli strings with phase tracking; drop terms with Y (expectation 0).
constexpr Terms gen(int q, bool xpart) {
    Terms T{};
    const unsigned base = xpart ? B_STR[q] : A_STR[q];
    T.w = 0;
    for (int j = 0; j < 8; ++j)
        if ((base >> (2*j)) & 3u) { T.supp[T.w] = j; T.w++; }
    T.n = 0;
    for (int b = 0; b < (1 << T.w); ++b) {
        unsigned str = 0; int ph = 0; float sg = 1.0f;
        for (int i = 0; i < T.w; ++i) {
            const int j = T.supp[i];
            const int pj = (base >> (2*j)) & 3;
            const bool sbr = ((b >> i) & 1) != 0;
            unsigned f = 0;
            if (pj == 3) { f = sbr ? B_STR[j] : A_STR[j]; if (sbr) sg = -sg; }
            else         { f = sbr ? A_STR[j] : B_STR[j]; }
            unsigned r = 0;
            for (int k = 0; k < 8; ++k) {
                const int pa = (str >> (2*k)) & 3, pb = (f >> (2*k)) & 3;
                r |= (unsigned)PMUL[pa][pb] << (2*k);
                ph = (ph + PPH[pa][pb]) & 3;
            }
            str = r;
        }
        bool dead = false; unsigned xm = 0, zm = 0;
        for (int k = 0; k < 8; ++k) {
            const int p = (str >> (2*k)) & 3;
            if (p == 2) dead = true;
            else if (p == 1) xm |= 1u << k;
            else if (p == 3) zm |= 1u << k;
        }
        if (ph & 1) dead = true;      // imaginary phase => contains Y => 0
        if (dead) continue;
        if (ph == 2) sg = -sg;
        T.sgn[T.n] = sg; T.sbits[T.n] = (unsigned char)b;
        T.xm[T.n] = (unsigned char)xm; T.zm[T.n] = (unsigned char)zm;
        T.n++;
    }
    return T;
}

constexpr Terms TA[8] = {gen(0,false),gen(1,false),gen(2,false),gen(3,false),
                         gen(4,false),gen(5,false),gen(6,false),gen(7,false)};
constexpr Terms TB[8] = {gen(0,true),gen(1,true),gen(2,true),gen(3,true),
                         gen(4,true),gen(5,true),gen(6,true),gen(7,true)};
} // namespace ct

__device__ __forceinline__ float ftanh(float x) {
    float e = __builtin_amdgcn_exp2f(x * 2.8853900817779268f);  // e^(2x)
    return (e - 1.0f) * __builtin_amdgcn_rcpf(e + 1.0f);
}
__device__ __forceinline__ float fcos(float x) { return __builtin_amdgcn_cosf(x * INV2PI); }
__device__ __forceinline__ float fsin(float x) { return __builtin_amdgcn_sinf(x * INV2PI); }

__global__ __launch_bounds__(256) void vqc_net(
    const float* __restrict__ x,
    const float* __restrict__ W_pi1, const float* __restrict__ b_pi1,
    const float* __restrict__ qw_pi,
    const float* __restrict__ W_pi2, const float* __restrict__ b_pi2,
    const float* __restrict__ W_v1, const float* __restrict__ b_v1,
    const float* __restrict__ qw_v,
    const float* __restrict__ W_v2, const float* __restrict__ b_v2,
    float* __restrict__ out)
{
    const int gid = blockIdx.x * 256 + threadIdx.x;   // one (sample,branch) per lane
    const int branch = gid >> 15;                     // 0 = pi, 1 = v (wave-uniform)
    const int s = gid & (BTOT - 1);

    const float* W1 = branch ? W_v1 : W_pi1;
    const float* b1 = branch ? b_v1 : b_pi1;
    const float* qw = branch ? qw_v : qw_pi;

    // ---- embedding: theta_j = tanh(x_s . W1_j + b1_j);  <X_j>=cos, <Z_j>=-sin ----
    const float4* xr = (const float4*)(x + s * 8);
    const float4 xa = xr[0], xb = xr[1];
    float xv[8], zv[8];
    #pragma unroll
    for (int j = 0; j < 8; ++j) {
        float a = b1[j];
        a = fmaf(xa.x, W1[j*8+0], a); a = fmaf(xa.y, W1[j*8+1], a);
        a = fmaf(xa.z, W1[j*8+2], a); a = fmaf(xa.w, W1[j*8+3], a);
        a = fmaf(xb.x, W1[j*8+4], a); a = fmaf(xb.y, W1[j*8+5], a);
        a = fmaf(xb.z, W1[j*8+6], a); a = fmaf(xb.w, W1[j*8+7], a);
        const float th = ftanh(a);
        xv[j] = fcos(th);
        zv[j] = -fsin(th);
    }

    // ---- gate trig (full angles; wave-uniform values, computed per lane) ----
    float c1[8], s1[8], c2[8], s2[8];
    #pragma unroll
    for (int j = 0; j < 8; ++j) {
        c1[j] = fcos(qw[j]);     s1[j] = fsin(qw[j]);       // layer k=0
        c2[j] = fcos(qw[8+j]);   s2[j] = fsin(qw[8+j]);     // layer k=1
    }

    // ---- observables: <Z_q> = c2q*EA_q - s2q*EB_q, compile-time term tables ----
    float y[8];
    #pragma unroll
    for (int q = 0; q < 8; ++q) {
        float EA = 0.0f;
        #pragma unroll
        for (int t = 0; t < 8; ++t) {
            if (t < ct::TA[q].n) {
                float cf = ct::TA[q].sgn[t];
                #pragma unroll
                for (int i = 0; i < 3; ++i)
                    if (i < ct::TA[q].w)
                        cf *= ((ct::TA[q].sbits[t] >> i) & 1) ? s1[ct::TA[q].supp[i]]
                                                              : c1[ct::TA[q].supp[i]];
                #pragma unroll
                for (int j = 0; j < 8; ++j) {
                    if ((ct::TA[q].xm[t] >> j) & 1) cf *= xv[j];
                    if ((ct::TA[q].zm[t] >> j) & 1) cf *= zv[j];
                }
                EA += cf;
            }
        }
        float EB = 0.0f;
        #pragma unroll
        for (int t = 0; t < 8; ++t) {
            if (t < ct::TB[q].n) {
                float cf = ct::TB[q].sgn[t];
                #pragma unroll
                for (int i = 0; i < 3; ++i)
                    if (i < ct::TB[q].w)
                        cf *= ((ct::TB[q].sbits[t] >> i) & 1) ? s1[ct::TB[q].supp[i]]
                                                              : c1[ct::TB[q].supp[i]];
                #pragma unroll
                for (int j = 0; j < 8; ++j) {
                    if ((ct::TB[q].xm[t] >> j) & 1) cf *= xv[j];
                    if ((ct::TB[q].zm[t] >> j) & 1) cf *= zv[j];
                }
                EB += cf;
            }
        }
        const float Zq = fmaf(c2[q], EA, -(s2[q] * EB));
        y[q] = ftanh(Zq);
    }

    // ---- output matvec ----
    if (branch == 0) {
        float4 o;
        {
            float a0 = b_pi2[0], a1 = b_pi2[1], a2 = b_pi2[2], a3 = b_pi2[3];
            #pragma unroll
            for (int j = 0; j < 8; ++j) {
                a0 = fmaf(y[j], W_pi2[0*8+j], a0);
                a1 = fmaf(y[j], W_pi2[1*8+j], a1);
                a2 = fmaf(y[j], W_pi2[2*8+j], a2);
                a3 = fmaf(y[j], W_pi2[3*8+j], a3);
            }
            o.x = a0; o.y = a1; o.z = a2; o.w = a3;
        }
        *(float4*)(out + s * 4) = o;
    } else {
        float acc = b_v2[0];
        #pragma unroll
        for (int j = 0; j < 8; ++j) acc = fmaf(y[j], W_v2[j], acc);
        out[4 * BTOT + s] = acc;
    }
}

extern "C" void kernel_launch(void* const* d_in, const int* in_sizes, int n_in,
                              void* d_out, int out_size, void* d_ws, size_t ws_size,
                              hipStream_t stream) {
    const float* x     = (const float*)d_in[0];
    const float* W_pi1 = (const float*)d_in[1];
    const float* b_pi1 = (const float*)d_in[2];
    const float* qw_pi = (const float*)d_in[3];
    const float* W_pi2 = (const float*)d_in[4];
    const float* b_pi2 = (const float*)d_in[5];
    const float* W_v1  = (const float*)d_in[6];
    const float* b_v1  = (const float*)d_in[7];
    const float* qw_v  = (const float*)d_in[8];
    const float* W_v2  = (const float*)d_in[9];
    const float* b_v2  = (const float*)d_in[10];
    float* out = (float*)d_out;

    const int blocks = (2 * BTOT) / 256;  // one lane per (sample, branch)
    vqc_net<<<blocks, 256, 0, stream>>>(
        x, W_pi1, b_pi1, qw_pi, W_pi2, b_pi2,
        W_v1, b_v1, qw_v, W_v2, b_v2, out);
}

// Round 8
// 9.464 us; speedup vs baseline: 11.7250x; 1.7657x over previous
//
#include <hip/hip_runtime.h>

#define BTOT 32768
#define INV2PI 0.15915494309189535f

// ======== compile-time Pauli algebra (Heisenberg back-propagation) ========
// Pauli codes: 0=I, 1=X, 2=Y, 3=Z. Strings packed 2 bits/qubit (qubit j at bits 2j).
namespace ct {
constexpr int PMUL[4][4] = {{0,1,2,3},{1,0,3,2},{2,3,0,1},{3,2,1,0}};
constexpr int PPH [4][4] = {{0,0,0,0},{0,0,1,3},{0,3,0,1},{0,1,3,0}};  // phase as power of i

// Conjugation images through one CNOT block (odd rank then even rank, backward):
constexpr unsigned A_STR[8] = {0x3u, 0xFu, 0x3Fu, 0xF0u, 0x3F0u, 0xF00u, 0x3F00u, 0xF000u};
// Z0 | Z0Z1 | Z0Z1Z2 | Z2Z3 | Z2Z3Z4 | Z4Z5 | Z4Z5Z6 | Z6Z7
constexpr unsigned B_STR[8] = {0x5u, 0x54u, 0x50u, 0x540u, 0x500u, 0x5400u, 0x5000u, 0x4000u};
// X0X1 | X1X2X3 | X2X3 | X3X4X5 | X4X5 | X5X6X7 | X6X7 | X7

struct Terms {
    int n; int w; int supp[3];
    float sgn[8]; unsigned char sbits[8]; unsigned char xm[8]; unsigned char zm[8];
};

constexpr Terms gen(int q, bool xpart) {
    Terms T{};
    const unsigned base = xpart ? B_STR[q] : A_STR[q];
    T.w = 0;
    for (int j = 0; j < 8; ++j)
        if ((base >> (2*j)) & 3u) { T.supp[T.w] = j; T.w++; }
    T.n = 0;
    for (int b = 0; b < (1 << T.w); ++b) {
        unsigned str = 0; int ph = 0; float sg = 1.0f;
        for (int i = 0; i < T.w; ++i) {
            const int j = T.supp[i];
            const int pj = (base >> (2*j)) & 3;
            const bool sbr = ((b >> i) & 1) != 0;
            unsigned f = 0;
            if (pj == 3) { f = sbr ? B_STR[j] : A_STR[j]; if (sbr) sg = -sg; }
            else         { f = sbr ? A_STR[j] : B_STR[j]; }
            unsigned r = 0;
            for (int k = 0; k < 8; ++k) {
                const int pa = (str >> (2*k)) & 3, pb = (f >> (2*k)) & 3;
                r |= (unsigned)PMUL[pa][pb] << (2*k);
                ph = (ph + PPH[pa][pb]) & 3;
            }
            str = r;
        }
        bool dead = false; unsigned xm = 0, zm = 0;
        for (int k = 0; k < 8; ++k) {
            const int p = (str >> (2*k)) & 3;
            if (p == 2) dead = true;
            else if (p == 1) xm |= 1u << k;
            else if (p == 3) zm |= 1u << k;
        }
        if (ph & 1) dead = true;
        if (dead) continue;
        if (ph == 2) sg = -sg;
        T.sgn[T.n] = sg; T.sbits[T.n] = (unsigned char)b;
        T.xm[T.n] = (unsigned char)xm; T.zm[T.n] = (unsigned char)zm;
        T.n++;
    }
    return T;
}

constexpr Terms TA[8] = {gen(0,false),gen(1,false),gen(2,false),gen(3,false),
                         gen(4,false),gen(5,false),gen(6,false),gen(7,false)};
constexpr Terms TB[8] = {gen(0,true),gen(1,true),gen(2,true),gen(3,true),
                         gen(4,true),gen(5,true),gen(6,true),gen(7,true)};

constexpr unsigned suppmask(unsigned str) {
    unsigned m = 0;
    for (int j = 0; j < 8; ++j) if ((str >> (2*j)) & 3u) m |= 1u << j;
    return m;
}
template<int W>
constexpr unsigned c1mask() {
    return suppmask(A_STR[2*W]) | suppmask(B_STR[2*W])
         | suppmask(A_STR[2*W+1]) | suppmask(B_STR[2*W+1]);
}
} // namespace ct

__device__ __forceinline__ float ftanh(float x) {
    float e = __builtin_amdgcn_exp2f(x * 2.8853900817779268f);  // e^(2x)
    return (e - 1.0f) * __builtin_amdgcn_rcpf(e + 1.0f);
}
__device__ __forceinline__ float fcos(float x) { return __builtin_amdgcn_cosf(x * INV2PI); }
__device__ __forceinline__ float fsin(float x) { return __builtin_amdgcn_sinf(x * INV2PI); }

// evaluate <Z_q> before final tanh (tables folded at compile time)
template<int Q>
__device__ __forceinline__ float eval_q(const float c1[8], const float s1[8],
                                        const float xv[8], const float zv[8],
                                        float c2, float s2)
{
    float EA = 0.0f;
    #pragma unroll
    for (int t = 0; t < 8; ++t) {
        if (t < ct::TA[Q].n) {
            float cf = ct::TA[Q].sgn[t];
            #pragma unroll
            for (int i = 0; i < 3; ++i)
                if (i < ct::TA[Q].w)
                    cf *= ((ct::TA[Q].sbits[t] >> i) & 1) ? s1[ct::TA[Q].supp[i]]
                                                          : c1[ct::TA[Q].supp[i]];
            #pragma unroll
            for (int j = 0; j < 8; ++j) {
                if ((ct::TA[Q].xm[t] >> j) & 1) cf *= xv[j];
                if ((ct::TA[Q].zm[t] >> j) & 1) cf *= zv[j];
            }
            EA += cf;
        }
    }
    float EB = 0.0f;
    #pragma unroll
    for (int t = 0; t < 8; ++t) {
        if (t < ct::TB[Q].n) {
            float cf = ct::TB[Q].sgn[t];
            #pragma unroll
            for (int i = 0; i < 3; ++i)
                if (i < ct::TB[Q].w)
                    cf *= ((ct::TB[Q].sbits[t] >> i) & 1) ? s1[ct::TB[Q].supp[i]]
                                                          : c1[ct::TB[Q].supp[i]];
            #pragma unroll
            for (int j = 0; j < 8; ++j) {
                if ((ct::TB[Q].xm[t] >> j) & 1) cf *= xv[j];
                if ((ct::TB[Q].zm[t] >> j) & 1) cf *= zv[j];
            }
            EB += cf;
        }
    }
    return fmaf(c2, EA, -(s2 * EB));
}

// wave W handles qubits 2W, 2W+1: embed -> LDS share -> terms -> y to LDS
template<int W>
__device__ __forceinline__ void pair_phase(
    const float* __restrict__ x, const float* __restrict__ W1,
    const float* __restrict__ b1, const float* __restrict__ qw,
    int lane, int s, float2 (*xz)[64], float (*ybuf)[64])
{
    constexpr int j0 = 2*W, j1 = 2*W + 1;

    // ---- embed 2 qubits ----
    const float4* xr = (const float4*)(x + s * 8);
    const float4 xa = xr[0], xb = xr[1];
    float a0 = b1[j0], a1 = b1[j1];
    a0 = fmaf(xa.x, W1[j0*8+0], a0); a0 = fmaf(xa.y, W1[j0*8+1], a0);
    a0 = fmaf(xa.z, W1[j0*8+2], a0); a0 = fmaf(xa.w, W1[j0*8+3], a0);
    a0 = fmaf(xb.x, W1[j0*8+4], a0); a0 = fmaf(xb.y, W1[j0*8+5], a0);
    a0 = fmaf(xb.z, W1[j0*8+6], a0); a0 = fmaf(xb.w, W1[j0*8+7], a0);
    a1 = fmaf(xa.x, W1[j1*8+0], a1); a1 = fmaf(xa.y, W1[j1*8+1], a1);
    a1 = fmaf(xa.z, W1[j1*8+2], a1); a1 = fmaf(xa.w, W1[j1*8+3], a1);
    a1 = fmaf(xb.x, W1[j1*8+4], a1); a1 = fmaf(xb.y, W1[j1*8+5], a1);
    a1 = fmaf(xb.z, W1[j1*8+6], a1); a1 = fmaf(xb.w, W1[j1*8+7], a1);
    const float th0 = ftanh(a0), th1 = ftanh(a1);
    float2 e0; e0.x = fcos(th0); e0.y = -fsin(th0);
    float2 e1; e1.x = fcos(th1); e1.y = -fsin(th1);
    xz[j0][lane] = e0;
    xz[j1][lane] = e1;
    __syncthreads();

    // ---- gate trig (only the support-union of this q-pair) ----
    constexpr unsigned m = ct::c1mask<W>();
    float c1[8], s1[8];
    #pragma unroll
    for (int j = 0; j < 8; ++j) {
        if ((m >> j) & 1) { c1[j] = fcos(qw[j]); s1[j] = fsin(qw[j]); }
    }
    const float c2a = fcos(qw[8+j0]), s2a = fsin(qw[8+j0]);
    const float c2b = fcos(qw[8+j1]), s2b = fsin(qw[8+j1]);

    // ---- gather all embed factors ----
    float xv[8], zv[8];
    #pragma unroll
    for (int j = 0; j < 8; ++j) {
        const float2 t = xz[j][lane];
        xv[j] = t.x; zv[j] = t.y;
    }

    const float y0 = ftanh(eval_q<j0>(c1, s1, xv, zv, c2a, s2a));
    const float y1 = ftanh(eval_q<j1>(c1, s1, xv, zv, c2b, s2b));
    ybuf[j0][lane] = y0;
    ybuf[j1][lane] = y1;
}

__global__ __launch_bounds__(256) void vqc_net(
    const float* __restrict__ x,
    const float* __restrict__ W_pi1, const float* __restrict__ b_pi1,
    const float* __restrict__ qw_pi,
    const float* __restrict__ W_pi2, const float* __restrict__ b_pi2,
    const float* __restrict__ W_v1, const float* __restrict__ b_v1,
    const float* __restrict__ qw_v,
    const float* __restrict__ W_v2, const float* __restrict__ b_v2,
    float* __restrict__ out)
{
    __shared__ float2 xz[8][64];     // embed factors  (4 KB)
    __shared__ float  ybuf[8][64];   // tanh'd <Z_q>   (2 KB)
    __shared__ float4 obuf[64];      // pi-output transpose (1 KB)

    const int tid = threadIdx.x;
    const int lane = tid & 63;
    const int w = tid >> 6;
    const int item = blockIdx.x * 64 + lane;   // block-uniform branch (32768 % 64 == 0)
    const int branch = item >> 15;             // 0 = pi, 1 = v
    const int s = item & (BTOT - 1);

    const float* W1 = branch ? W_v1 : W_pi1;
    const float* b1 = branch ? b_v1 : b_pi1;
    const float* qw = branch ? qw_v : qw_pi;

    switch (w) {
        case 0:  pair_phase<0>(x, W1, b1, qw, lane, s, xz, ybuf); break;
        case 1:  pair_phase<1>(x, W1, b1, qw, lane, s, xz, ybuf); break;
        case 2:  pair_phase<2>(x, W1, b1, qw, lane, s, xz, ybuf); break;
        default: pair_phase<3>(x, W1, b1, qw, lane, s, xz, ybuf); break;
    }
    __syncthreads();

    if (branch == 0) {
        // wave w computes logit w for its lane's sample
        float o = b_pi2[w];
        #pragma unroll
        for (int j = 0; j < 8; ++j) o = fmaf(ybuf[j][lane], W_pi2[w*8+j], o);
        ((float*)&obuf[lane])[w] = o;
        __syncthreads();
        if (w == 0) *(float4*)(out + s * 4) = obuf[lane];
    } else {
        if (w == 0) {
            float o = b_v2[0];
            #pragma unroll
            for (int j = 0; j < 8; ++j) o = fmaf(ybuf[j][lane], W_v2[j], o);
            out[4 * BTOT + s] = o;
        }
    }
}

extern "C" void kernel_launch(void* const* d_in, const int* in_sizes, int n_in,
                              void* d_out, int out_size, void* d_ws, size_t ws_size,
                              hipStream_t stream) {
    const float* x     = (const float*)d_in[0];
    const float* W_pi1 = (const float*)d_in[1];
    const float* b_pi1 = (const float*)d_in[2];
    const float* qw_pi = (const float*)d_in[3];
    const float* W_pi2 = (const float*)d_in[4];
    const float* b_pi2 = (const float*)d_in[5];
    const float* W_v1  = (const float*)d_in[6];
    const float* b_v1  = (const float*)d_in[7];
    const float* qw_v  = (const float*)d_in[8];
    const float* W_v2  = (const float*)d_in[9];
    const float* b_v2  = (const float*)d_in[10];
    float* out = (float*)d_out;

    const int blocks = (2 * BTOT) / 64;  // 64 items/block, 4 waves share each item set
    vqc_net<<<blocks, 256, 0, stream>>>(
        x, W_pi1, b_pi1, qw_pi, W_pi2, b_pi2,
        W_v1, b_v1, qw_v, W_v2, b_v2, out);
}